// Round 1
// baseline (1803.429 us; speedup 1.0000x reference)
//
#include <hip/hip_runtime.h>
#include <math.h>

#define HID 256

__device__ __forceinline__ float gelu_f(float x){
  return 0.5f * x * (1.0f + erff(x * 0.70710678118654752440f));
}

// Generic row-major tiled GEMM: C = epilogue(A[M,K] @ B[K,N] + bias)
// mode: 0 plain, 1 relu, 2 qscale (col scale pvec[col>>7]/sqrt(128)), 3 skip-blend
// a_gelu: apply exact gelu to A elements on load
// a_rows: optional row-gather indices for A
__global__ __launch_bounds__(256) void gemm_k(
    const float* __restrict__ A, int lda,
    const float* __restrict__ B, int ldb,
    const float* __restrict__ bias,
    float* __restrict__ C, int ldc,
    int M, int N, int K,
    int mode, int a_gelu,
    const int* __restrict__ a_rows,
    const float* __restrict__ pvec,
    const float* __restrict__ skipx,
    const float* __restrict__ skip_gate)
{
  __shared__ __align__(16) float As[16][68];  // As[k][row]
  __shared__ __align__(16) float Bs[16][68];  // Bs[k][col]
  const int t  = threadIdx.x;
  const int tx = t & 15, ty = t >> 4;
  const int row0 = blockIdx.y * 64;
  const int col0 = blockIdx.x * 64;
  float acc[4][4] = {};

  for (int k0 = 0; k0 < K; k0 += 16){
#pragma unroll
    for (int i = 0; i < 4; i++){
      int idx = t + i*256;
      int r = idx >> 4, kk = idx & 15;
      int gr = row0 + r;
      float v = 0.f;
      if (gr < M){
        int ar = a_rows ? a_rows[gr] : gr;
        v = A[(long long)ar*lda + (k0+kk)];
        if (a_gelu) v = gelu_f(v);
      }
      As[kk][r] = v;
    }
#pragma unroll
    for (int i = 0; i < 4; i++){
      int idx = t + i*256;
      int kk = idx >> 6, n = idx & 63;
      int gc = col0 + n;
      Bs[kk][n] = (gc < N) ? B[(long long)(k0+kk)*ldb + gc] : 0.f;
    }
    __syncthreads();
#pragma unroll
    for (int kk = 0; kk < 16; kk++){
      float4 av = *(const float4*)&As[kk][ty*4];
      float4 bv = *(const float4*)&Bs[kk][tx*4];
      acc[0][0] += av.x*bv.x; acc[0][1] += av.x*bv.y; acc[0][2] += av.x*bv.z; acc[0][3] += av.x*bv.w;
      acc[1][0] += av.y*bv.x; acc[1][1] += av.y*bv.y; acc[1][2] += av.y*bv.z; acc[1][3] += av.y*bv.w;
      acc[2][0] += av.z*bv.x; acc[2][1] += av.z*bv.y; acc[2][2] += av.z*bv.z; acc[2][3] += av.z*bv.w;
      acc[3][0] += av.w*bv.x; acc[3][1] += av.w*bv.y; acc[3][2] += av.w*bv.z; acc[3][3] += av.w*bv.w;
    }
    __syncthreads();
  }

  float gate = 0.f;
  if (mode == 3) gate = 1.f/(1.f + expf(-(*skip_gate)));
#pragma unroll
  for (int i = 0; i < 4; i++){
    int gr = row0 + ty*4 + i;
    if (gr >= M) continue;
#pragma unroll
    for (int j = 0; j < 4; j++){
      int gc = col0 + tx*4 + j;
      if (gc >= N) continue;
      float v = acc[i][j] + (bias ? bias[gc] : 0.f);
      if (mode == 1) v = fmaxf(v, 0.f);
      else if (mode == 2) v *= pvec[gc >> 7] * 0.08838834764831845f;  // p/sqrt(128)
      else if (mode == 3) v = gate*v + (1.f-gate)*skipx[(long long)gr*HID + gc];
      C[(long long)gr*ldc + gc] = v;
    }
  }
}

// C[M,N] = sigmoid(A[M,K] @ B[N,K]^T), A,B row-major (NT)
__global__ __launch_bounds__(256) void gemm_nt_sig_k(
    const float* __restrict__ A, const float* __restrict__ B,
    float* __restrict__ C, int M, int N, int K)
{
  __shared__ __align__(16) float As[16][68];
  __shared__ __align__(16) float Bs[16][68];
  const int t  = threadIdx.x;
  const int tx = t & 15, ty = t >> 4;
  const int row0 = blockIdx.y * 64;
  const int col0 = blockIdx.x * 64;
  float acc[4][4] = {};

  for (int k0 = 0; k0 < K; k0 += 16){
#pragma unroll
    for (int i = 0; i < 4; i++){
      int idx = t + i*256;
      int r = idx >> 4, kk = idx & 15;
      int gr = row0 + r;
      As[kk][r] = (gr < M) ? A[(long long)gr*K + k0 + kk] : 0.f;
    }
#pragma unroll
    for (int i = 0; i < 4; i++){
      int idx = t + i*256;
      int n = idx >> 4, kk = idx & 15;
      int gc = col0 + n;
      Bs[kk][n] = (gc < N) ? B[(long long)gc*K + k0 + kk] : 0.f;
    }
    __syncthreads();
#pragma unroll
    for (int kk = 0; kk < 16; kk++){
      float4 av = *(const float4*)&As[kk][ty*4];
      float4 bv = *(const float4*)&Bs[kk][tx*4];
      acc[0][0] += av.x*bv.x; acc[0][1] += av.x*bv.y; acc[0][2] += av.x*bv.z; acc[0][3] += av.x*bv.w;
      acc[1][0] += av.y*bv.x; acc[1][1] += av.y*bv.y; acc[1][2] += av.y*bv.z; acc[1][3] += av.y*bv.w;
      acc[2][0] += av.z*bv.x; acc[2][1] += av.z*bv.y; acc[2][2] += av.z*bv.z; acc[2][3] += av.z*bv.w;
      acc[3][0] += av.w*bv.x; acc[3][1] += av.w*bv.y; acc[3][2] += av.w*bv.z; acc[3][3] += av.w*bv.w;
    }
    __syncthreads();
  }
#pragma unroll
  for (int i = 0; i < 4; i++){
    int gr = row0 + ty*4 + i;
    if (gr >= M) continue;
#pragma unroll
    for (int j = 0; j < 4; j++){
      int gc = col0 + tx*4 + j;
      if (gc >= N) continue;
      C[(long long)gr*N + gc] = 1.f/(1.f + expf(-acc[i][j]));
    }
  }
}

// bias fold: out[h*128+e] = sum_d b[h*128+d] * rel[h,d,e]
__global__ __launch_bounds__(256) void fold_bias_k(
    const float* __restrict__ b, const float* __restrict__ rel, float* __restrict__ out)
{
  int i = threadIdx.x;
  int h = i >> 7, e = i & 127;
  float s = 0.f;
  for (int d = 0; d < 128; d++) s += b[h*128+d] * rel[(h*128+d)*128 + e];
  out[i] = s;
}

// ---- CSR build ----
__global__ void hist_k(const int* __restrict__ dst, int E, int* __restrict__ deg){
  int i = blockIdx.x*256 + threadIdx.x;
  if (i < E) atomicAdd(&deg[dst[i]], 1);
}

__global__ __launch_bounds__(256) void partial_sum_k(
    const int* __restrict__ deg, int n, int* __restrict__ part)
{
  __shared__ int sdata[4];
  int i = blockIdx.x*256 + threadIdx.x;
  int v = (i < n) ? deg[i] : 0;
#pragma unroll
  for (int o = 32; o; o >>= 1) v += __shfl_xor(v, o);
  int lane = threadIdx.x & 63, wid = threadIdx.x >> 6;
  if (lane == 0) sdata[wid] = v;
  __syncthreads();
  if (threadIdx.x == 0) part[blockIdx.x] = sdata[0]+sdata[1]+sdata[2]+sdata[3];
}

__global__ __launch_bounds__(256) void scan_part_k(
    int* __restrict__ part, int nb, int* __restrict__ total_out)
{
  __shared__ int ws[4]; __shared__ int tot;
  int t = threadIdx.x;
  int v = (t < nb) ? part[t] : 0;
  int lane = t & 63, wid = t >> 6;
  int x = v;
#pragma unroll
  for (int o = 1; o < 64; o <<= 1){ int y = __shfl_up(x, o); if (lane >= o) x += y; }
  if (lane == 63) ws[wid] = x;
  __syncthreads();
  if (t == 0){ int s = 0; for (int i = 0; i < 4; i++){ int tmp = ws[i]; ws[i] = s; s += tmp; } tot = s; }
  __syncthreads();
  int excl = x - v + ws[wid];
  if (t < nb) part[t] = excl;
  if (t == 0) *total_out = tot;
}

__global__ __launch_bounds__(256) void scan_offs_k(
    const int* __restrict__ deg, int n, const int* __restrict__ part,
    int* __restrict__ offs, int* __restrict__ cursor)
{
  __shared__ int ws[4];
  int t = threadIdx.x;
  int i = blockIdx.x*256 + t;
  int v = (i < n) ? deg[i] : 0;
  int lane = t & 63, wid = t >> 6;
  int x = v;
#pragma unroll
  for (int o = 1; o < 64; o <<= 1){ int y = __shfl_up(x, o); if (lane >= o) x += y; }
  if (lane == 63) ws[wid] = x;
  __syncthreads();
  int pre = 0;
  for (int k = 0; k < wid; k++) pre += ws[k];
  if (i < n){ int o = part[blockIdx.x] + x - v + pre; offs[i] = o; cursor[i] = o; }
}

__global__ void scatter_k(const int* __restrict__ src, const int* __restrict__ dst, int E,
                          int* __restrict__ cursor, int* __restrict__ esrc){
  int i = blockIdx.x*256 + threadIdx.x;
  if (i < E){ int p = atomicAdd(&cursor[dst[i]], 1); esrc[p] = src[i]; }
}

// ---- segment attention: one block per dst node ----
// q pre-scaled by p_b[h]/sqrt(D). agg = (sum_e exp(q.k_e) * v_e) / (sum_e exp + 1e-16)
__global__ __launch_bounds__(256) void attn_k(
    const float* __restrict__ q, const float* __restrict__ ke, const float* __restrict__ ve,
    const int* __restrict__ offs, const int* __restrict__ esrc,
    float* __restrict__ agg)
{
  int dst = blockIdx.x;
  int t = threadIdx.x;
  __shared__ float qs[256];
  __shared__ float wbuf[8];
  __shared__ float den[2];
  qs[t] = q[(long long)dst*256 + t];
  if (t < 2) den[t] = 0.f;
  __syncthreads();
  int beg = offs[dst], end = offs[dst+1];
  float num = 0.f;
  int h = t >> 7;
  for (int base = beg; base < end; base += 4){
    int nE = min(4, end - base);
    int wave = t >> 6, lane = t & 63;
    if (wave < nE){
      const float2* kp = (const float2*)(ke + (long long)esrc[base+wave]*256);
      const float2* qp = (const float2*)qs;
      float2 k0 = kp[lane],      q0 = qp[lane];
      float2 k1 = kp[64+lane],   q1 = qp[64+lane];
      float p0 = q0.x*k0.x + q0.y*k0.y;
      float p1 = q1.x*k1.x + q1.y*k1.y;
#pragma unroll
      for (int o = 32; o; o >>= 1){ p0 += __shfl_xor(p0, o); p1 += __shfl_xor(p1, o); }
      if (lane == 0){ wbuf[wave*2+0] = expf(p0); wbuf[wave*2+1] = expf(p1); }
    }
    __syncthreads();
    for (int j = 0; j < nE; j++){
      num += wbuf[j*2 + h] * ve[(long long)esrc[base+j]*256 + t];
    }
    if (t < 2){ for (int j = 0; j < nE; j++) den[t] += wbuf[j*2 + t]; }
    __syncthreads();
  }
  agg[(long long)dst*256 + t] = num / (den[h] + 1e-16f);
}

extern "C" void kernel_launch(void* const* d_in, const int* in_sizes, int n_in,
                              void* d_out, int out_size, void* d_ws, size_t ws_size,
                              hipStream_t stream)
{
  (void)n_in; (void)out_size; (void)ws_size;
  const float* x_author    = (const float*)d_in[0];
  const float* x_paper     = (const float*)d_in[1];
  const int*   eb_src      = (const int*)d_in[4];
  const int*   eb_dst      = (const int*)d_in[5];
  const int*   input_nodes = (const int*)d_in[6];
  const float* W_in_a  = (const float*)d_in[7];
  const float* b_in_a  = (const float*)d_in[8];
  const float* W_in_p  = (const float*)d_in[9];
  const float* b_in_p  = (const float*)d_in[10];
  const float* Wkqv_a  = (const float*)d_in[11];
  const float* bkqv_a  = (const float*)d_in[12];
  const float* Wkqv_p  = (const float*)d_in[13];
  const float* bkqv_p  = (const float*)d_in[14];
  const float* Wk_rel_b= (const float*)d_in[17];
  const float* Wv_rel_b= (const float*)d_in[18];
  const float* p_b     = (const float*)d_in[20];
  const float* Wout_a  = (const float*)d_in[21];
  const float* bout_a  = (const float*)d_in[22];
  const float* skip_a  = (const float*)d_in[25];
  const float* W_dec   = (const float*)d_in[27];
  const float* b_dec   = (const float*)d_in[28];

  const int Na = in_sizes[0] / 128;
  const int Np = in_sizes[1] / 128;
  const int E  = in_sizes[4];
  const int NI = in_sizes[6];

  // workspace layout (~158 MB): 3 big node buffers + small stuff + CSR
  char* w = (char*)d_ws;
  auto alloc = [&](size_t bytes)->void*{
    void* p = (void*)w; w += (bytes + 255) & ~(size_t)255; return p;
  };
  float* xa  = (float*)alloc((size_t)Na*HID*4);   // xa (alive until za blend)
  float* xp  = (float*)alloc((size_t)Np*HID*4);   // xp, later reused as agg
  float* q   = (float*)alloc((size_t)Na*HID*4);   // q (scaled), later reused as za
  float* zin = (float*)alloc((size_t)NI*HID*4);
  float* Wk_fold = (float*)alloc(HID*HID*4);
  float* Wv_fold = (float*)alloc(HID*HID*4);
  float* bk_fold = (float*)alloc(HID*4);
  float* bv_fold = (float*)alloc(HID*4);
  int* deg    = (int*)alloc((size_t)Na*4);
  int* offs   = (int*)alloc((size_t)(Na+1)*4);
  int* cursor = (int*)alloc((size_t)Na*4);
  int* part   = (int*)alloc(1024);
  int* esrc   = (int*)alloc((size_t)E*4);
  // d_out doubles as ke/ve scratch (2 * Np*256 floats == out_size exactly)
  float* ke = (float*)d_out;
  float* ve = (float*)d_out + (size_t)Np*HID;
  float* agg = xp;
  float* za  = q;

  dim3 blk(256);
  // xa = relu(x_author @ W_in_a + b)
  gemm_k<<<dim3(4,(Na+63)/64), blk, 0, stream>>>(x_author,128, W_in_a,256, b_in_a,
      xa,256, Na,256,128, 1,0,nullptr,nullptr,nullptr,nullptr);
  // xp = relu(x_paper @ W_in_p + b)
  gemm_k<<<dim3(4,(Np+63)/64), blk, 0, stream>>>(x_paper,128, W_in_p,256, b_in_p,
      xp,256, Np,256,128, 1,0,nullptr,nullptr,nullptr,nullptr);
  // q = (xa @ Wkqv_a[:,256:512] + b) * p_b[h]/sqrt(128)
  gemm_k<<<dim3(4,(Na+63)/64), blk, 0, stream>>>(xa,256, Wkqv_a+256,768, bkqv_a+256,
      q,256, Na,256,256, 2,0,nullptr,p_b,nullptr,nullptr);
  // fold Wk_rel_b / Wv_rel_b into kqv weights
  for (int h = 0; h < 2; h++){
    gemm_k<<<dim3(2,4), blk, 0, stream>>>(Wkqv_p + h*128,768, Wk_rel_b + h*128*128,128, nullptr,
        Wk_fold + h*128,256, 256,128,128, 0,0,nullptr,nullptr,nullptr,nullptr);
    gemm_k<<<dim3(2,4), blk, 0, stream>>>(Wkqv_p + 512 + h*128,768, Wv_rel_b + h*128*128,128, nullptr,
        Wv_fold + h*128,256, 256,128,128, 0,0,nullptr,nullptr,nullptr,nullptr);
  }
  fold_bias_k<<<1,256,0,stream>>>(bkqv_p,     Wk_rel_b, bk_fold);
  fold_bias_k<<<1,256,0,stream>>>(bkqv_p+512, Wv_rel_b, bv_fold);
  // ke = xp @ Wk_fold + bk_fold ; ve = xp @ Wv_fold + bv_fold
  gemm_k<<<dim3(4,(Np+63)/64), blk, 0, stream>>>(xp,256, Wk_fold,256, bk_fold,
      ke,256, Np,256,256, 0,0,nullptr,nullptr,nullptr,nullptr);
  gemm_k<<<dim3(4,(Np+63)/64), blk, 0, stream>>>(xp,256, Wv_fold,256, bv_fold,
      ve,256, Np,256,256, 0,0,nullptr,nullptr,nullptr,nullptr);
  // CSR build over edge_b (dst = authors)
  hipMemsetAsync(deg, 0, (size_t)Na*4, stream);
  hist_k<<<(E+255)/256, blk, 0, stream>>>(eb_dst, E, deg);
  int nb = (Na+255)/256;
  partial_sum_k<<<nb, blk, 0, stream>>>(deg, Na, part);
  scan_part_k<<<1, blk, 0, stream>>>(part, nb, offs+Na);
  scan_offs_k<<<nb, blk, 0, stream>>>(deg, Na, part, offs, cursor);
  scatter_k<<<(E+255)/256, blk, 0, stream>>>(eb_src, eb_dst, E, cursor, esrc);
  // attention -> agg (reuses xp buffer)
  attn_k<<<Na, blk, 0, stream>>>(q, ke, ve, offs, esrc, agg);
  // za = sigmoid(skip_a)*(gelu(agg)@Wout_a + b) + (1-g)*xa  (za reuses q buffer)
  gemm_k<<<dim3(4,(Na+63)/64), blk, 0, stream>>>(agg,256, Wout_a,256, bout_a,
      za,256, Na,256,256, 3,1,nullptr,nullptr, xa, skip_a);
  // zin = za[input_nodes] @ W_dec + b_dec
  gemm_k<<<dim3(4,(NI+63)/64), blk, 0, stream>>>(za,256, W_dec,256, b_dec,
      zin,256, NI,256,256, 0,0,input_nodes,nullptr,nullptr,nullptr);
  // out = sigmoid(zin @ za^T)
  gemm_nt_sig_k<<<dim3((Na+63)/64,(NI+63)/64), blk, 0, stream>>>(zin, za, (float*)d_out, NI, Na, 256);
}

// Round 2
// 1135.496 us; speedup vs baseline: 1.5882x; 1.5882x over previous
//
#include <hip/hip_runtime.h>
#include <math.h>

#define HID 256

typedef __bf16 bf16_t;
typedef __attribute__((ext_vector_type(8))) __bf16 bf16x8;
typedef __attribute__((ext_vector_type(4))) __bf16 bf16x4;
typedef __attribute__((ext_vector_type(4))) float f32x4;

__device__ __forceinline__ float gelu_f(float x){
  return 0.5f * x * (1.0f + erff(x * 0.70710678118654752440f));
}

// ---------------- fp32 tiled GEMM (kept for the tiny weight-fold GEMMs) ----------------
__global__ __launch_bounds__(256) void gemm_k(
    const float* __restrict__ A, int lda,
    const float* __restrict__ B, int ldb,
    const float* __restrict__ bias,
    float* __restrict__ C, int ldc,
    int M, int N, int K)
{
  __shared__ __align__(16) float As[16][68];
  __shared__ __align__(16) float Bs[16][68];
  const int t  = threadIdx.x;
  const int tx = t & 15, ty = t >> 4;
  const int row0 = blockIdx.y * 64;
  const int col0 = blockIdx.x * 64;
  float acc[4][4] = {};
  for (int k0 = 0; k0 < K; k0 += 16){
#pragma unroll
    for (int i = 0; i < 4; i++){
      int idx = t + i*256;
      int r = idx >> 4, kk = idx & 15;
      int gr = row0 + r;
      As[kk][r] = (gr < M) ? A[(long long)gr*lda + (k0+kk)] : 0.f;
    }
#pragma unroll
    for (int i = 0; i < 4; i++){
      int idx = t + i*256;
      int kk = idx >> 6, n = idx & 63;
      int gc = col0 + n;
      Bs[kk][n] = (gc < N) ? B[(long long)(k0+kk)*ldb + gc] : 0.f;
    }
    __syncthreads();
#pragma unroll
    for (int kk = 0; kk < 16; kk++){
      float4 av = *(const float4*)&As[kk][ty*4];
      float4 bv = *(const float4*)&Bs[kk][tx*4];
      acc[0][0] += av.x*bv.x; acc[0][1] += av.x*bv.y; acc[0][2] += av.x*bv.z; acc[0][3] += av.x*bv.w;
      acc[1][0] += av.y*bv.x; acc[1][1] += av.y*bv.y; acc[1][2] += av.y*bv.z; acc[1][3] += av.y*bv.w;
      acc[2][0] += av.z*bv.x; acc[2][1] += av.z*bv.y; acc[2][2] += av.z*bv.z; acc[2][3] += av.z*bv.w;
      acc[3][0] += av.w*bv.x; acc[3][1] += av.w*bv.y; acc[3][2] += av.w*bv.z; acc[3][3] += av.w*bv.w;
    }
    __syncthreads();
  }
#pragma unroll
  for (int i = 0; i < 4; i++){
    int gr = row0 + ty*4 + i;
    if (gr >= M) continue;
#pragma unroll
    for (int j = 0; j < 4; j++){
      int gc = col0 + tx*4 + j;
      if (gc >= N) continue;
      C[(long long)gr*ldc + gc] = acc[i][j] + (bias ? bias[gc] : 0.f);
    }
  }
}

// ---------------- bf16 MFMA NT GEMM: C = epi(A[M,K] @ Bt[N,K]^T + bias) ----------------
// mode: 0 plain->bf16, 1 relu->bf16, 2 qscale->bf16, 3 skipblend->bf16, 4 sigmoid->f32
__global__ __launch_bounds__(256) void mfma_gemm_k(
    const bf16_t* __restrict__ A, int lda,
    const bf16_t* __restrict__ Bt, int ldb,
    const float* __restrict__ bias,
    void* __restrict__ Cout, int ldc,
    int M, int N, int K,
    int mode, int a_gelu,
    const int* __restrict__ a_rows,
    const float* __restrict__ pvec,
    const bf16_t* __restrict__ skipx,
    const float* __restrict__ skip_gate)
{
  constexpr int LDSS = 72;   // 64 + 8 pad (16B) breaks 128B-stride bank aliasing
  __shared__ bf16_t As[128*LDSS];
  __shared__ bf16_t Bs[128*LDSS];
  const int t = threadIdx.x;
  const int wave = t >> 6, lane = t & 63;
  const int quad = lane >> 4, l16 = lane & 15;
  const int row0 = blockIdx.y*128, col0 = blockIdx.x*128;
  const int R = (wave>>1)*64, Cb = (wave&1)*64;
  f32x4 acc[4][4] = {};

  for (int k0 = 0; k0 < K; k0 += 64){
#pragma unroll
    for (int i = 0; i < 4; i++){
      int id = t + i*256;
      int r = id >> 3, c = (id & 7)*8;
      int gr = row0 + r;
      bf16x8 v = {};
      if (gr < M){
        int ar = a_rows ? a_rows[gr] : gr;
        v = *(const bf16x8*)(A + (long long)ar*lda + k0 + c);
        if (a_gelu){
#pragma unroll
          for (int j = 0; j < 8; j++) v[j] = (bf16_t)gelu_f((float)v[j]);
        }
      }
      *(bf16x8*)(As + r*LDSS + c) = v;
    }
#pragma unroll
    for (int i = 0; i < 4; i++){
      int id = t + i*256;
      int r = id >> 3, c = (id & 7)*8;
      int gc = col0 + r;
      bf16x8 v = {};
      if (gc < N) v = *(const bf16x8*)(Bt + (long long)gc*ldb + k0 + c);
      *(bf16x8*)(Bs + r*LDSS + c) = v;
    }
    __syncthreads();
#pragma unroll
    for (int kk = 0; kk < 64; kk += 32){
      bf16x8 af[4], bfr[4];
#pragma unroll
      for (int i = 0; i < 4; i++) af[i]  = *(const bf16x8*)(As + (R  + 16*i + l16)*LDSS + kk + quad*8);
#pragma unroll
      for (int j = 0; j < 4; j++) bfr[j] = *(const bf16x8*)(Bs + (Cb + 16*j + l16)*LDSS + kk + quad*8);
#pragma unroll
      for (int i = 0; i < 4; i++)
#pragma unroll
        for (int j = 0; j < 4; j++)
          acc[i][j] = __builtin_amdgcn_mfma_f32_16x16x32_bf16(af[i], bfr[j], acc[i][j], 0, 0, 0);
    }
    __syncthreads();
  }

  float gate = 0.f;
  if (mode == 3) gate = 1.f/(1.f + expf(-(*skip_gate)));
#pragma unroll
  for (int i = 0; i < 4; i++){
#pragma unroll
    for (int j = 0; j < 4; j++){
#pragma unroll
      for (int r = 0; r < 4; r++){
        int gr = row0 + R + 16*i + quad*4 + r;
        int gc = col0 + Cb + 16*j + l16;
        if (gr >= M || gc >= N) continue;
        float v = acc[i][j][r] + (bias ? bias[gc] : 0.f);
        if (mode == 1) v = fmaxf(v, 0.f);
        else if (mode == 2) v *= pvec[gc >> 7] * 0.08838834764831845f;
        else if (mode == 3) v = gate*v + (1.f - gate)*(float)skipx[(long long)gr*HID + gc];
        if (mode == 4) ((float*)Cout)[(long long)gr*ldc + gc] = 1.f/(1.f + expf(-v));
        else ((bf16_t*)Cout)[(long long)gr*ldc + gc] = (bf16_t)v;
      }
    }
  }
}

// ---------------- conversions ----------------
__global__ void cast_k(const float* __restrict__ x, bf16_t* __restrict__ y, int n4){
  int i = blockIdx.x*256 + threadIdx.x;
  if (i < n4){
    float4 v = *(const float4*)(x + (size_t)i*4);
    bf16x4 o = {(bf16_t)v.x, (bf16_t)v.y, (bf16_t)v.z, (bf16_t)v.w};
    *(bf16x4*)(y + (size_t)i*4) = o;
  }
}

// W[K,N] (lda) fp32 -> Wt[N,K] bf16
__global__ void tcast_k(const float* __restrict__ W, int lda, bf16_t* __restrict__ Wt, int K, int N){
  __shared__ float tile[32][33];
  int bx = blockIdx.x*32, by = blockIdx.y*32;
  int tx = threadIdx.x, ty = threadIdx.y;
  for (int i = 0; i < 32; i += 8){
    int k = by + ty + i, n = bx + tx;
    tile[ty+i][tx] = (k < K && n < N) ? W[(long long)k*lda + n] : 0.f;
  }
  __syncthreads();
  for (int i = 0; i < 32; i += 8){
    int n = bx + ty + i, k = by + tx;
    if (n < N && k < K) Wt[(long long)n*K + k] = (bf16_t)tile[tx][ty+i];
  }
}

// bias fold: out[h*128+e] = sum_d b[h*128+d] * rel[h,d,e]
__global__ __launch_bounds__(256) void fold_bias_k(
    const float* __restrict__ b, const float* __restrict__ rel, float* __restrict__ out)
{
  int i = threadIdx.x;
  int h = i >> 7, e = i & 127;
  float s = 0.f;
  for (int d = 0; d < 128; d++) s += b[h*128+d] * rel[(h*128+d)*128 + e];
  out[i] = s;
}

// ---------------- CSR build ----------------
__global__ void hist_k(const int* __restrict__ dst, int E, int* __restrict__ deg){
  int i = blockIdx.x*256 + threadIdx.x;
  if (i < E) atomicAdd(&deg[dst[i]], 1);
}

__global__ __launch_bounds__(256) void partial_sum_k(
    const int* __restrict__ deg, int n, int* __restrict__ part)
{
  __shared__ int sdata[4];
  int i = blockIdx.x*256 + threadIdx.x;
  int v = (i < n) ? deg[i] : 0;
#pragma unroll
  for (int o = 32; o; o >>= 1) v += __shfl_xor(v, o);
  int lane = threadIdx.x & 63, wid = threadIdx.x >> 6;
  if (lane == 0) sdata[wid] = v;
  __syncthreads();
  if (threadIdx.x == 0) part[blockIdx.x] = sdata[0]+sdata[1]+sdata[2]+sdata[3];
}

__global__ __launch_bounds__(256) void scan_part_k(
    int* __restrict__ part, int nb, int* __restrict__ total_out)
{
  __shared__ int ws[4]; __shared__ int tot;
  int t = threadIdx.x;
  int v = (t < nb) ? part[t] : 0;
  int lane = t & 63, wid = t >> 6;
  int x = v;
#pragma unroll
  for (int o = 1; o < 64; o <<= 1){ int y = __shfl_up(x, o); if (lane >= o) x += y; }
  if (lane == 63) ws[wid] = x;
  __syncthreads();
  if (t == 0){ int s = 0; for (int i = 0; i < 4; i++){ int tmp = ws[i]; ws[i] = s; s += tmp; } tot = s; }
  __syncthreads();
  int excl = x - v + ws[wid];
  if (t < nb) part[t] = excl;
  if (t == 0) *total_out = tot;
}

__global__ __launch_bounds__(256) void scan_offs_k(
    const int* __restrict__ deg, int n, const int* __restrict__ part,
    int* __restrict__ offs, int* __restrict__ cursor)
{
  __shared__ int ws[4];
  int t = threadIdx.x;
  int i = blockIdx.x*256 + t;
  int v = (i < n) ? deg[i] : 0;
  int lane = t & 63, wid = t >> 6;
  int x = v;
#pragma unroll
  for (int o = 1; o < 64; o <<= 1){ int y = __shfl_up(x, o); if (lane >= o) x += y; }
  if (lane == 63) ws[wid] = x;
  __syncthreads();
  int pre = 0;
  for (int k = 0; k < wid; k++) pre += ws[k];
  if (i < n){ int o = part[blockIdx.x] + x - v + pre; offs[i] = o; cursor[i] = o; }
}

__global__ void scatter_k(const int* __restrict__ src, const int* __restrict__ dst, int E,
                          int* __restrict__ cursor, int* __restrict__ esrc){
  int i = blockIdx.x*256 + threadIdx.x;
  if (i < E){ int p = atomicAdd(&cursor[dst[i]], 1); esrc[p] = src[i]; }
}

// ---------------- segment attention (bf16 q/ke/ve, fp32 accum) ----------------
__global__ __launch_bounds__(256) void attn_bf_k(
    const bf16_t* __restrict__ q, const bf16_t* __restrict__ ke, const bf16_t* __restrict__ ve,
    const int* __restrict__ offs, const int* __restrict__ esrc,
    bf16_t* __restrict__ agg)
{
  int dst = blockIdx.x;
  int t = threadIdx.x;
  __shared__ float qs[256];
  __shared__ float wbuf[8];
  __shared__ float den[2];
  qs[t] = (float)q[(long long)dst*256 + t];
  if (t < 2) den[t] = 0.f;
  __syncthreads();
  int beg = offs[dst], end = offs[dst+1];
  float num = 0.f;
  int h = t >> 7;
  int wave = t >> 6, lane = t & 63;
  for (int base = beg; base < end; base += 4){
    int nE = min(4, end - base);
    if (wave < nE){
      const bf16_t* kp = ke + (long long)esrc[base+wave]*256;
      bf16x4 kv = *(const bf16x4*)(kp + lane*4);
      float p = qs[lane*4+0]*(float)kv[0] + qs[lane*4+1]*(float)kv[1]
              + qs[lane*4+2]*(float)kv[2] + qs[lane*4+3]*(float)kv[3];
#pragma unroll
      for (int o = 16; o; o >>= 1) p += __shfl_xor(p, o);
      if ((lane & 31) == 0) wbuf[wave*2 + (lane>>5)] = expf(p);
    }
    __syncthreads();
    for (int j = 0; j < nE; j++)
      num += wbuf[j*2 + h] * (float)ve[(long long)esrc[base+j]*256 + t];
    if (t < 2){ for (int j = 0; j < nE; j++) den[t] += wbuf[j*2 + t]; }
    __syncthreads();
  }
  agg[(long long)dst*256 + t] = (bf16_t)(num / (den[h] + 1e-16f));
}

extern "C" void kernel_launch(void* const* d_in, const int* in_sizes, int n_in,
                              void* d_out, int out_size, void* d_ws, size_t ws_size,
                              hipStream_t stream)
{
  (void)n_in; (void)out_size; (void)ws_size;
  const float* x_author    = (const float*)d_in[0];
  const float* x_paper     = (const float*)d_in[1];
  const int*   eb_src      = (const int*)d_in[4];
  const int*   eb_dst      = (const int*)d_in[5];
  const int*   input_nodes = (const int*)d_in[6];
  const float* W_in_a  = (const float*)d_in[7];
  const float* b_in_a  = (const float*)d_in[8];
  const float* W_in_p  = (const float*)d_in[9];
  const float* b_in_p  = (const float*)d_in[10];
  const float* Wkqv_a  = (const float*)d_in[11];
  const float* bkqv_a  = (const float*)d_in[12];
  const float* Wkqv_p  = (const float*)d_in[13];
  const float* bkqv_p  = (const float*)d_in[14];
  const float* Wk_rel_b= (const float*)d_in[17];
  const float* Wv_rel_b= (const float*)d_in[18];
  const float* p_b     = (const float*)d_in[20];
  const float* Wout_a  = (const float*)d_in[21];
  const float* bout_a  = (const float*)d_in[22];
  const float* skip_a  = (const float*)d_in[25];
  const float* W_dec   = (const float*)d_in[27];
  const float* b_dec   = (const float*)d_in[28];

  const int Na = in_sizes[0] / 128;
  const int Np = in_sizes[1] / 128;
  const int E  = in_sizes[4];
  const int NI = in_sizes[6];

  char* w = (char*)d_ws;
  auto alloc = [&](size_t bytes)->void*{
    void* p = (void*)w; w += (bytes + 255) & ~(size_t)255; return p;
  };
  bf16_t* xab   = (bf16_t*)alloc((size_t)Na*128*2);  // raw bf16 inputs; region reused as aggb
  bf16_t* xpb   = (bf16_t*)alloc((size_t)Np*128*2);
  bf16_t* xa_bf = (bf16_t*)alloc((size_t)Na*HID*2);
  bf16_t* xp_bf = (bf16_t*)alloc((size_t)Np*HID*2);
  bf16_t* qb    = (bf16_t*)alloc((size_t)Na*HID*2);  // reused as za
  bf16_t* zin   = (bf16_t*)alloc((size_t)NI*HID*2);
  bf16_t* Wt_in_a = (bf16_t*)alloc(128*HID*2);
  bf16_t* Wt_in_p = (bf16_t*)alloc(128*HID*2);
  bf16_t* Wt_q    = (bf16_t*)alloc(HID*HID*2);
  bf16_t* Wkt     = (bf16_t*)alloc(HID*HID*2);
  bf16_t* Wvt     = (bf16_t*)alloc(HID*HID*2);
  bf16_t* Wt_out  = (bf16_t*)alloc(HID*HID*2);
  bf16_t* Wt_dec  = (bf16_t*)alloc(HID*HID*2);
  float* Wk_fold = (float*)alloc(HID*HID*4);
  float* Wv_fold = (float*)alloc(HID*HID*4);
  float* bk_fold = (float*)alloc(HID*4);
  float* bv_fold = (float*)alloc(HID*4);
  int* deg    = (int*)alloc((size_t)Na*4);
  int* offs   = (int*)alloc((size_t)(Na+1)*4);
  int* cursor = (int*)alloc((size_t)Na*4);
  int* part   = (int*)alloc(1024);
  int* esrc   = (int*)alloc((size_t)E*4);

  // ke/ve (bf16) live in d_out (dead before final GEMM writes it)
  bf16_t* keb = (bf16_t*)d_out;
  bf16_t* veb = keb + (size_t)Np*HID;
  bf16_t* aggb = xab;   // [Na,256] bf16 == xab+xpb region (25.6 MB contiguous)
  bf16_t* zab  = qb;

  dim3 blk(256);
  dim3 tblk(32, 8);

  // bf16 casts of raw inputs
  cast_k<<<(Na*128/4 + 255)/256, blk, 0, stream>>>(x_author, xab, Na*128/4);
  cast_k<<<(Np*128/4 + 255)/256, blk, 0, stream>>>(x_paper,  xpb, Np*128/4);
  // weight transpose+cast
  tcast_k<<<dim3(8,4),  tblk, 0, stream>>>(W_in_a, 256, Wt_in_a, 128, 256);
  tcast_k<<<dim3(8,4),  tblk, 0, stream>>>(W_in_p, 256, Wt_in_p, 128, 256);
  tcast_k<<<dim3(8,8),  tblk, 0, stream>>>(Wkqv_a + 256, 768, Wt_q, 256, 256);
  tcast_k<<<dim3(8,8),  tblk, 0, stream>>>(Wout_a, 256, Wt_out, 256, 256);
  tcast_k<<<dim3(8,8),  tblk, 0, stream>>>(W_dec,  256, Wt_dec, 256, 256);
  // fold Wk_rel_b / Wv_rel_b into kqv_p weights (fp32, tiny)
  for (int h = 0; h < 2; h++){
    gemm_k<<<dim3(2,4), blk, 0, stream>>>(Wkqv_p + h*128, 768, Wk_rel_b + h*128*128, 128, nullptr,
        Wk_fold + h*128, 256, 256, 128, 128);
    gemm_k<<<dim3(2,4), blk, 0, stream>>>(Wkqv_p + 512 + h*128, 768, Wv_rel_b + h*128*128, 128, nullptr,
        Wv_fold + h*128, 256, 256, 128, 128);
  }
  fold_bias_k<<<1,256,0,stream>>>(bkqv_p,     Wk_rel_b, bk_fold);
  fold_bias_k<<<1,256,0,stream>>>(bkqv_p+512, Wv_rel_b, bv_fold);
  tcast_k<<<dim3(8,8),  tblk, 0, stream>>>(Wk_fold, 256, Wkt, 256, 256);
  tcast_k<<<dim3(8,8),  tblk, 0, stream>>>(Wv_fold, 256, Wvt, 256, 256);

  dim3 gN(2, (Na+127)/128);
  // xa = relu(x_author @ W_in_a + b)
  mfma_gemm_k<<<gN, blk, 0, stream>>>(xab, 128, Wt_in_a, 128, b_in_a, xa_bf, HID,
      Na, 256, 128, 1, 0, nullptr, nullptr, nullptr, nullptr);
  // xp = relu(x_paper @ W_in_p + b)
  mfma_gemm_k<<<dim3(2,(Np+127)/128), blk, 0, stream>>>(xpb, 128, Wt_in_p, 128, b_in_p, xp_bf, HID,
      Np, 256, 128, 1, 0, nullptr, nullptr, nullptr, nullptr);
  // q = (xa @ Wq + b) * p_b[h]/sqrt(128)
  mfma_gemm_k<<<gN, blk, 0, stream>>>(xa_bf, HID, Wt_q, HID, bkqv_a + 256, qb, HID,
      Na, 256, 256, 2, 0, nullptr, p_b, nullptr, nullptr);
  // ke = xp @ Wk_fold + bk ; ve = xp @ Wv_fold + bv
  mfma_gemm_k<<<dim3(2,(Np+127)/128), blk, 0, stream>>>(xp_bf, HID, Wkt, HID, bk_fold, keb, HID,
      Np, 256, 256, 0, 0, nullptr, nullptr, nullptr, nullptr);
  mfma_gemm_k<<<dim3(2,(Np+127)/128), blk, 0, stream>>>(xp_bf, HID, Wvt, HID, bv_fold, veb, HID,
      Np, 256, 256, 0, 0, nullptr, nullptr, nullptr, nullptr);
  // CSR over edge_b (dst = authors)
  hipMemsetAsync(deg, 0, (size_t)Na*4, stream);
  hist_k<<<(E+255)/256, blk, 0, stream>>>(eb_dst, E, deg);
  int nb = (Na+255)/256;
  partial_sum_k<<<nb, blk, 0, stream>>>(deg, Na, part);
  scan_part_k<<<1, blk, 0, stream>>>(part, nb, offs+Na);
  scan_offs_k<<<nb, blk, 0, stream>>>(deg, Na, part, offs, cursor);
  scatter_k<<<(E+255)/256, blk, 0, stream>>>(eb_src, eb_dst, E, cursor, esrc);
  // attention
  attn_bf_k<<<Na, blk, 0, stream>>>(qb, keb, veb, offs, esrc, aggb);
  // za = g*(gelu(agg)@Wout + b) + (1-g)*xa
  mfma_gemm_k<<<gN, blk, 0, stream>>>(aggb, HID, Wt_out, HID, bout_a, zab, HID,
      Na, 256, 256, 3, 1, nullptr, nullptr, xa_bf, skip_a);
  // zin = za[input_nodes] @ W_dec + b
  mfma_gemm_k<<<dim3(2,(NI+127)/128), blk, 0, stream>>>(zab, HID, Wt_dec, HID, b_dec, zin, HID,
      NI, 256, 256, 0, 0, input_nodes, nullptr, nullptr, nullptr);
  // out = sigmoid(zin @ za^T)  (fp32 out)
  mfma_gemm_k<<<dim3((Na+127)/128, (NI+127)/128), blk, 0, stream>>>(zin, HID, zab, HID, nullptr,
      (float*)d_out, Na, NI, Na, 256, 4, 0, nullptr, nullptr, nullptr, nullptr);
}

// Round 4
// 920.721 us; speedup vs baseline: 1.9587x; 1.2333x over previous
//
#include <hip/hip_runtime.h>
#include <math.h>

#define HID 256

typedef __bf16 bf16_t;
typedef __attribute__((ext_vector_type(8))) __bf16 bf16x8;
typedef __attribute__((ext_vector_type(4))) __bf16 bf16x4;
typedef __attribute__((ext_vector_type(4))) float f32x4;

__device__ __forceinline__ float gelu_f(float x){
  return 0.5f * x * (1.0f + erff(x * 0.70710678118654752440f));
}

// ---------------- bf16 MFMA NT GEMM: C = epi(A[M,K] @ Bt[N,K]^T + bias) ----------------
// mode: 0 plain->bf16, 1 relu->bf16, 2 qscale->bf16, 3 skipblend->bf16, 4 sigmoid->f32
// a_f32: A is fp32 (converted to bf16 during LDS staging)
__global__ __launch_bounds__(256) void mfma_gemm_k(
    const void* __restrict__ A, int lda,
    const bf16_t* __restrict__ Bt, int ldb,
    const float* __restrict__ bias,
    void* __restrict__ Cout, int ldc,
    int M, int N, int K,
    int mode, int a_gelu, int a_f32,
    const int* __restrict__ a_rows,
    const float* __restrict__ pvec,
    const bf16_t* __restrict__ skipx,
    const float* __restrict__ skip_gate)
{
  constexpr int LDSS = 72;   // 64 + 8 pad (16B) breaks 128B-stride bank aliasing
  __shared__ bf16_t As[128*LDSS];
  __shared__ bf16_t Bs[128*LDSS];
  const int t = threadIdx.x;
  const int wave = t >> 6, lane = t & 63;
  const int quad = lane >> 4, l16 = lane & 15;
  const int row0 = blockIdx.y*128, col0 = blockIdx.x*128;
  const int R = (wave>>1)*64, Cb = (wave&1)*64;
  f32x4 acc[4][4] = {};

  for (int k0 = 0; k0 < K; k0 += 64){
#pragma unroll
    for (int i = 0; i < 4; i++){
      int id = t + i*256;
      int r = id >> 3, c = (id & 7)*8;
      int gr = row0 + r;
      bf16x8 v = {};
      if (gr < M){
        int ar = a_rows ? a_rows[gr] : gr;
        if (a_f32){
          const float* p = (const float*)A + (long long)ar*lda + k0 + c;
          float4 f0 = *(const float4*)p;
          float4 f1 = *(const float4*)(p + 4);
          v[0]=(bf16_t)f0.x; v[1]=(bf16_t)f0.y; v[2]=(bf16_t)f0.z; v[3]=(bf16_t)f0.w;
          v[4]=(bf16_t)f1.x; v[5]=(bf16_t)f1.y; v[6]=(bf16_t)f1.z; v[7]=(bf16_t)f1.w;
        } else {
          v = *(const bf16x8*)((const bf16_t*)A + (long long)ar*lda + k0 + c);
          if (a_gelu){
#pragma unroll
            for (int j = 0; j < 8; j++) v[j] = (bf16_t)gelu_f((float)v[j]);
          }
        }
      }
      *(bf16x8*)(As + r*LDSS + c) = v;
    }
#pragma unroll
    for (int i = 0; i < 4; i++){
      int id = t + i*256;
      int r = id >> 3, c = (id & 7)*8;
      int gc = col0 + r;
      bf16x8 v = {};
      if (gc < N) v = *(const bf16x8*)(Bt + (long long)gc*ldb + k0 + c);
      *(bf16x8*)(Bs + r*LDSS + c) = v;
    }
    __syncthreads();
#pragma unroll
    for (int kk = 0; kk < 64; kk += 32){
      bf16x8 af[4], bfr[4];
#pragma unroll
      for (int i = 0; i < 4; i++) af[i]  = *(const bf16x8*)(As + (R  + 16*i + l16)*LDSS + kk + quad*8);
#pragma unroll
      for (int j = 0; j < 4; j++) bfr[j] = *(const bf16x8*)(Bs + (Cb + 16*j + l16)*LDSS + kk + quad*8);
#pragma unroll
      for (int i = 0; i < 4; i++)
#pragma unroll
        for (int j = 0; j < 4; j++)
          acc[i][j] = __builtin_amdgcn_mfma_f32_16x16x32_bf16(af[i], bfr[j], acc[i][j], 0, 0, 0);
    }
    __syncthreads();
  }

  float gate = 0.f;
  if (mode == 3) gate = 1.f/(1.f + expf(-(*skip_gate)));
#pragma unroll
  for (int i = 0; i < 4; i++){
#pragma unroll
    for (int j = 0; j < 4; j++){
#pragma unroll
      for (int r = 0; r < 4; r++){
        int gr = row0 + R + 16*i + quad*4 + r;
        int gc = col0 + Cb + 16*j + l16;
        if (gr >= M || gc >= N) continue;
        float v = acc[i][j][r] + (bias ? bias[gc] : 0.f);
        if (mode == 1) v = fmaxf(v, 0.f);
        else if (mode == 2) v *= pvec[gc >> 7] * 0.08838834764831845f;
        else if (mode == 3) v = gate*v + (1.f - gate)*(float)skipx[(long long)gr*HID + gc];
        if (mode == 4) ((float*)Cout)[(long long)gr*ldc + gc] = 1.f/(1.f + expf(-v));
        else ((bf16_t*)Cout)[(long long)gr*ldc + gc] = (bf16_t)v;
      }
    }
  }
}

// ---------------- fused weight transpose+cast: W[K,N](lda) fp32 -> Wt[N,K] bf16 ----------------
struct TW { const float* W; bf16_t* out; int lda; int K; int N; };

__global__ __launch_bounds__(256) void prep_weights_k(TW w0, TW w1, TW w2, TW w3, TW w4){
  TW tw;
  switch (blockIdx.z){
    case 0: tw = w0; break; case 1: tw = w1; break; case 2: tw = w2; break;
    case 3: tw = w3; break; default: tw = w4; break;
  }
  __shared__ float tile[32][33];
  int bx = blockIdx.x*32, by = blockIdx.y*32;
  if (by >= tw.K || bx >= tw.N) return;
  int tx = threadIdx.x, ty = threadIdx.y;
  for (int i = 0; i < 32; i += 8){
    int k = by + ty + i, n = bx + tx;
    tile[ty+i][tx] = (k < tw.K && n < tw.N) ? tw.W[(long long)k*tw.lda + n] : 0.f;
  }
  __syncthreads();
  for (int i = 0; i < 32; i += 8){
    int n = bx + ty + i, k = by + tx;
    if (n < tw.N && k < tw.K) tw.out[(long long)n*tw.K + k] = (bf16_t)tile[tx][ty+i];
  }
}

// ---------------- fold Wk_rel/Wv_rel into kqv_p weights, output transposed bf16 ----------------
// Wkvt[n'][m] = sum_k Wkqv_p[m, off + k] * rel[h, k, n],  n' = kv*256 + h*128 + n, off = kv*512 + h*128
// bkv[n'] = sum_k bkqv_p[off + k] * rel[h, k, n]
__global__ __launch_bounds__(256) void prep_fold_k(
    const float* __restrict__ Wkqv_p, const float* __restrict__ bkqv_p,
    const float* __restrict__ Wk_rel, const float* __restrict__ Wv_rel,
    bf16_t* __restrict__ Wkvt, float* __restrict__ bkv)
{
  int np = blockIdx.x;            // 0..511
  int kv = np >> 8, h = (np >> 7) & 1, n = np & 127;
  int off = kv*512 + h*128;
  const float* rel = (kv ? Wv_rel : Wk_rel) + h*128*128 + n;  // column n, stride 128
  __shared__ float relcol[128];
  int t = threadIdx.x;
  if (t < 128) relcol[t] = rel[t*128];
  __syncthreads();
  int m = t;                      // 0..255
  const float* wp = Wkqv_p + (long long)m*768 + off;
  float acc = 0.f;
#pragma unroll 8
  for (int k = 0; k < 128; k++) acc += wp[k] * relcol[k];
  Wkvt[(long long)np*256 + m] = (bf16_t)acc;
  if (t == 0){
    float b = 0.f;
    for (int k = 0; k < 128; k++) b += bkqv_p[off + k] * relcol[k];
    bkv[np] = b;
  }
}

// ---------------- CSR build ----------------
__global__ void hist_k(const int* __restrict__ dst, int E, int* __restrict__ deg){
  int i = blockIdx.x*256 + threadIdx.x;
  if (i < E) atomicAdd(&deg[dst[i]], 1);
}

__global__ __launch_bounds__(256) void partial_sum_k(
    const int* __restrict__ deg, int n, int* __restrict__ part)
{
  __shared__ int sdata[4];
  int i = blockIdx.x*256 + threadIdx.x;
  int v = (i < n) ? deg[i] : 0;
#pragma unroll
  for (int o = 32; o; o >>= 1) v += __shfl_xor(v, o);
  int lane = threadIdx.x & 63, wid = threadIdx.x >> 6;
  if (lane == 0) sdata[wid] = v;
  __syncthreads();
  if (threadIdx.x == 0) part[blockIdx.x] = sdata[0]+sdata[1]+sdata[2]+sdata[3];
}

__global__ __launch_bounds__(256) void scan_part_k(
    int* __restrict__ part, int nb, int* __restrict__ total_out)
{
  __shared__ int ws[4]; __shared__ int tot;
  int t = threadIdx.x;
  int v = (t < nb) ? part[t] : 0;
  int lane = t & 63, wid = t >> 6;
  int x = v;
#pragma unroll
  for (int o = 1; o < 64; o <<= 1){ int y = __shfl_up(x, o); if (lane >= o) x += y; }
  if (lane == 63) ws[wid] = x;
  __syncthreads();
  if (t == 0){ int s = 0; for (int i = 0; i < 4; i++){ int tmp = ws[i]; ws[i] = s; s += tmp; } tot = s; }
  __syncthreads();
  int excl = x - v + ws[wid];
  if (t < nb) part[t] = excl;
  if (t == 0) *total_out = tot;
}

__global__ __launch_bounds__(256) void scan_offs_k(
    const int* __restrict__ deg, int n, const int* __restrict__ part,
    int* __restrict__ offs, int* __restrict__ cursor)
{
  __shared__ int ws[4];
  int t = threadIdx.x;
  int i = blockIdx.x*256 + t;
  int v = (i < n) ? deg[i] : 0;
  int lane = t & 63, wid = t >> 6;
  int x = v;
#pragma unroll
  for (int o = 1; o < 64; o <<= 1){ int y = __shfl_up(x, o); if (lane >= o) x += y; }
  if (lane == 63) ws[wid] = x;
  __syncthreads();
  int pre = 0;
  for (int k = 0; k < wid; k++) pre += ws[k];
  if (i < n){ int o = part[blockIdx.x] + x - v + pre; offs[i] = o; cursor[i] = o; }
}

__global__ void scatter_k(const int* __restrict__ src, const int* __restrict__ dst, int E,
                          int* __restrict__ cursor, int2* __restrict__ epair){
  int i = blockIdx.x*256 + threadIdx.x;
  if (i < E){
    int s = src[i], d = dst[i];
    int p = atomicAdd(&cursor[d], 1);
    epair[p] = make_int2(s, d);
  }
}

// ---------------- attention phase L: one wave per edge, per-head logits ----------------
// lanes 0-31: head 0 (elems 0-127), lanes 32-63: head 1 (elems 128-255)
// w[e] = (exp(q[dst]·ke[src])_h0, exp(...)_h1)
__global__ __launch_bounds__(256) void attn_logit_k(
    const bf16_t* __restrict__ q, const bf16_t* __restrict__ keve,
    const int2* __restrict__ epair, int E, float2* __restrict__ w)
{
  int gid = blockIdx.x*256 + threadIdx.x;
  int e = gid >> 6, lane = gid & 63;
  if (e >= E) return;
  int2 sd = epair[e];
  bf16x4 qv = *(const bf16x4*)(q    + (size_t)sd.y*256 + lane*4);
  bf16x4 kv = *(const bf16x4*)(keve + (size_t)sd.x*512 + lane*4);
  float p = (float)qv[0]*(float)kv[0] + (float)qv[1]*(float)kv[1]
          + (float)qv[2]*(float)kv[2] + (float)qv[3]*(float)kv[3];
#pragma unroll
  for (int o = 16; o; o >>= 1) p += __shfl_xor(p, o);   // reduce within 32-lane half = one head
  if ((lane & 31) == 0)
    ((float*)w)[(size_t)e*2 + (lane >> 5)] = expf(p);
}

// ---------------- attention phase A: one wave per dst, barrier-free weighted sum ----------------
__global__ __launch_bounds__(256) void attn_agg_k(
    const bf16_t* __restrict__ keve, const float2* __restrict__ w,
    const int* __restrict__ offs, const int2* __restrict__ epair,
    int Na, bf16_t* __restrict__ agg)
{
  int gid = blockIdx.x*256 + threadIdx.x;
  int dst = gid >> 6, lane = gid & 63;
  if (dst >= Na) return;
  int h = lane >> 5;              // this lane's 4 v-components belong to head h
  int beg = offs[dst], end = offs[dst+1];
  float n0=0.f, n1=0.f, n2=0.f, n3=0.f, den=0.f;
#pragma unroll 4
  for (int i = beg; i < end; i++){
    float2 wv = w[i];
    float wi = h ? wv.y : wv.x;
    int src = epair[i].x;
    bf16x4 v = *(const bf16x4*)(keve + (size_t)src*512 + 256 + lane*4);
    n0 += wi*(float)v[0]; n1 += wi*(float)v[1];
    n2 += wi*(float)v[2]; n3 += wi*(float)v[3];
    den += wi;
  }
  float r = 1.f/(den + 1e-16f);
  bf16x4 o = {(bf16_t)(n0*r), (bf16_t)(n1*r), (bf16_t)(n2*r), (bf16_t)(n3*r)};
  *(bf16x4*)(agg + (size_t)dst*256 + lane*4) = o;
}

extern "C" void kernel_launch(void* const* d_in, const int* in_sizes, int n_in,
                              void* d_out, int out_size, void* d_ws, size_t ws_size,
                              hipStream_t stream)
{
  (void)n_in; (void)out_size; (void)ws_size;
  const float* x_author    = (const float*)d_in[0];
  const float* x_paper     = (const float*)d_in[1];
  const int*   eb_src      = (const int*)d_in[4];
  const int*   eb_dst      = (const int*)d_in[5];
  const int*   input_nodes = (const int*)d_in[6];
  const float* W_in_a  = (const float*)d_in[7];
  const float* b_in_a  = (const float*)d_in[8];
  const float* W_in_p  = (const float*)d_in[9];
  const float* b_in_p  = (const float*)d_in[10];
  const float* Wkqv_a  = (const float*)d_in[11];
  const float* bkqv_a  = (const float*)d_in[12];
  const float* Wkqv_p  = (const float*)d_in[13];
  const float* bkqv_p  = (const float*)d_in[14];
  const float* Wk_rel_b= (const float*)d_in[17];
  const float* Wv_rel_b= (const float*)d_in[18];
  const float* p_b     = (const float*)d_in[20];
  const float* Wout_a  = (const float*)d_in[21];
  const float* bout_a  = (const float*)d_in[22];
  const float* skip_a  = (const float*)d_in[25];
  const float* W_dec   = (const float*)d_in[27];
  const float* b_dec   = (const float*)d_in[28];

  const int Na = in_sizes[0] / 128;
  const int Np = in_sizes[1] / 128;
  const int E  = in_sizes[4];
  const int NI = in_sizes[6];

  char* w = (char*)d_ws;
  auto alloc = [&](size_t bytes)->void*{
    void* p = (void*)w; w += (bytes + 255) & ~(size_t)255; return p;
  };
  bf16_t* xa_bf = (bf16_t*)alloc((size_t)Na*HID*2);
  bf16_t* xp_bf = (bf16_t*)alloc((size_t)Np*HID*2);
  bf16_t* qb    = (bf16_t*)alloc((size_t)Na*HID*2);  // reused as za after attention
  bf16_t* aggb  = (bf16_t*)alloc((size_t)Na*HID*2);
  bf16_t* zin   = (bf16_t*)alloc((size_t)NI*HID*2);
  bf16_t* Wt_in_a = (bf16_t*)alloc(128*HID*2);
  bf16_t* Wt_in_p = (bf16_t*)alloc(128*HID*2);
  bf16_t* Wt_q    = (bf16_t*)alloc(HID*HID*2);
  bf16_t* Wt_out  = (bf16_t*)alloc(HID*HID*2);
  bf16_t* Wt_dec  = (bf16_t*)alloc(HID*HID*2);
  bf16_t* Wkvt    = (bf16_t*)alloc((size_t)512*HID*2);
  float*  bkv     = (float*)alloc(512*4);
  float2* wlog    = (float2*)alloc((size_t)E*8);
  int* deg    = (int*)alloc((size_t)Na*4);
  int* offs   = (int*)alloc((size_t)(Na+1)*4);
  int* cursor = (int*)alloc((size_t)Na*4);
  int* part   = (int*)alloc(1024);
  int2* epair = (int2*)alloc((size_t)E*8);

  // keve [Np,512] bf16 (ke||ve interleaved per row) lives in d_out (51.2 of 102.4 MB),
  // dead before the final GEMM overwrites d_out.
  bf16_t* keve = (bf16_t*)d_out;
  bf16_t* zab  = qb;

  dim3 blk(256);

  // fused weight transposes (fp32 -> bf16, K-major)
  TW tw0 = { W_in_a,       Wt_in_a, 256, 128, 256 };
  TW tw1 = { W_in_p,       Wt_in_p, 256, 128, 256 };
  TW tw2 = { Wkqv_a + 256, Wt_q,    768, 256, 256 };
  TW tw3 = { Wout_a,       Wt_out,  256, 256, 256 };
  TW tw4 = { W_dec,        Wt_dec,  256, 256, 256 };
  prep_weights_k<<<dim3(8,8,5), dim3(32,8), 0, stream>>>(tw0, tw1, tw2, tw3, tw4);
  // fold rel-matrices into kqv_p (transposed bf16 out) + folded bias
  prep_fold_k<<<512, blk, 0, stream>>>(Wkqv_p, bkqv_p, Wk_rel_b, Wv_rel_b, Wkvt, bkv);

  dim3 gNa(2, (Na+127)/128);
  dim3 gNp(2, (Np+127)/128);
  // xa = relu(x_author @ W_in_a + b)   (fp32 A staged directly)
  mfma_gemm_k<<<gNa, blk, 0, stream>>>(x_author, 128, Wt_in_a, 128, b_in_a, xa_bf, HID,
      Na, 256, 128, 1, 0, 1, nullptr, nullptr, nullptr, nullptr);
  // xp = relu(x_paper @ W_in_p + b)
  mfma_gemm_k<<<gNp, blk, 0, stream>>>(x_paper, 128, Wt_in_p, 128, b_in_p, xp_bf, HID,
      Np, 256, 128, 1, 0, 1, nullptr, nullptr, nullptr, nullptr);
  // q = (xa @ Wq + b) * p_b[h]/sqrt(128)
  mfma_gemm_k<<<gNa, blk, 0, stream>>>(xa_bf, HID, Wt_q, HID, bkqv_a + 256, qb, HID,
      Na, 256, 256, 2, 0, 0, nullptr, p_b, nullptr, nullptr);
  // keve = xp @ [Wk_fold || Wv_fold] + [bk||bv]   (N=512, interleaved rows)
  mfma_gemm_k<<<dim3(4,(Np+127)/128), blk, 0, stream>>>(xp_bf, HID, Wkvt, HID, bkv, keve, 512,
      Np, 512, 256, 0, 0, 0, nullptr, nullptr, nullptr, nullptr);
  // CSR over edge_b (dst = authors)
  hipMemsetAsync(deg, 0, (size_t)Na*4, stream);
  hist_k<<<(E+255)/256, blk, 0, stream>>>(eb_dst, E, deg);
  int nb = (Na+255)/256;
  partial_sum_k<<<nb, blk, 0, stream>>>(deg, Na, part);
  scan_part_k<<<1, blk, 0, stream>>>(part, nb, offs+Na);
  scan_offs_k<<<nb, blk, 0, stream>>>(deg, Na, part, offs, cursor);
  scatter_k<<<(E+255)/256, blk, 0, stream>>>(eb_src, eb_dst, E, cursor, epair);
  // attention, two barrier-free phases (per-head weights)
  attn_logit_k<<<E/4 + 1, blk, 0, stream>>>(qb, keve, epair, E, wlog);
  attn_agg_k<<<(Na+3)/4, blk, 0, stream>>>(keve, wlog, offs, epair, Na, aggb);
  // za = g*(gelu(agg)@Wout + b) + (1-g)*xa   (za reuses q buffer)
  mfma_gemm_k<<<gNa, blk, 0, stream>>>(aggb, HID, Wt_out, HID, bout_a, zab, HID,
      Na, 256, 256, 3, 1, 0, nullptr, nullptr, xa_bf, skip_a);
  // zin = za[input_nodes] @ W_dec + b
  mfma_gemm_k<<<dim3(2,(NI+127)/128), blk, 0, stream>>>(zab, HID, Wt_dec, HID, b_dec, zin, HID,
      NI, 256, 256, 0, 0, 0, input_nodes, nullptr, nullptr, nullptr);
  // out = sigmoid(zin @ za^T)  (fp32 out)
  mfma_gemm_k<<<dim3((Na+127)/128, (NI+127)/128), blk, 0, stream>>>(zin, HID, zab, HID, nullptr,
      (float*)d_out, Na, NI, Na, 256, 4, 0, 0, nullptr, nullptr, nullptr, nullptr);
}